// Round 6
// baseline (167.451 us; speedup 1.0000x reference)
//
#include <hip/hip_runtime.h>
#include <hip/hip_bf16.h>
#include <float.h>

#define DEPTH_PARAM 0.5f
#define LENGTH_PENALTY 1.5f

__global__ void init_out_kernel(float* out) { out[0] = 0.0f; }

// 256-thread block = 4 waves = 2 rows. Each wave scans ONE array of ONE row
// (wave&1==0 -> y_pred, wave&1==1 -> y_true): simple rolled loop, 1 load +
// compare chain per iteration, ~R1-level register pressure (no manual
// batching — R4/R5 proved the allocator demotes it to scratch).
// Waves merge argmaxes via LDS; pred-wave computes the tail with one 8-lane
// group per tree level; mean fused via atomicAdd into pre-zeroed out[0].
__global__ __launch_bounds__(256) void hier_row_kernel(
    const float* __restrict__ y_pred,
    const float* __restrict__ y_true,
    const float* __restrict__ class_weights,
    const int* __restrict__ path_ids,
    const int* __restrict__ path_len,
    const int* __restrict__ sib_start,
    const int* __restrict__ sib_size,
    float* __restrict__ out,
    int C, int D, int Bsz)
{
    const int wid     = threadIdx.x >> 6;     // 0..3
    const int lane    = threadIdx.x & 63;
    const int is_true = wid & 1;              // which array this wave scans
    int row = blockIdx.x * 2 + (wid >> 1);
    bool edge_dup = false;
    if (row >= Bsz) { row = Bsz - 1; edge_dup = true; }

    const float* __restrict__ src =
        (is_true ? y_true : y_pred) + (size_t)row * C;
    const float4* __restrict__ src4 = (const float4*)src;
    const int C4 = C >> 2;                    // 682 for C=2728

    // ---- single-array argmax: rolled loop, 1 float4 load / iter ----
    float bv = -FLT_MAX; int bi = 0;
    for (int i = lane; i < C4; i += 64) {
        const float4 v = src4[i];
        const int base = i << 2;
        if (v.x > bv) { bv = v.x; bi = base + 0; }
        if (v.y > bv) { bv = v.y; bi = base + 1; }
        if (v.z > bv) { bv = v.z; bi = base + 2; }
        if (v.w > bv) { bv = v.w; bi = base + 3; }
    }
    for (int c = (C4 << 2) + lane; c < C; c += 64) {
        const float v = src[c];
        if (v > bv) { bv = v; bi = c; }
    }

    // ---- butterfly reduce: all lanes end with (max, first-index) ----
    for (int m = 1; m < 64; m <<= 1) {
        const float ov = __shfl_xor(bv, m);
        const int   oi = __shfl_xor(bi, m);
        if (ov > bv || (ov == bv && oi < bi)) { bv = ov; bi = oi; }
    }

    // ---- publish per-wave result ----
    __shared__ int s_idx[4];
    if (lane == 0) s_idx[wid] = bi;
    __syncthreads();

    // ---- tail: pred-wave of each row pair ----
    if (is_true == 0 && !edge_dup) {
        const int pred_top = bi;              // own result (all lanes have it)
        const int true_top = s_idx[wid | 1];  // partner wave's result (broadcast)
        const int lp = path_len[pred_top];
        const int lt = path_len[true_top];
        const int lmin = lp < lt ? lp : lt;

        const float* __restrict__ yp = y_pred + (size_t)row * C;

        const int l = lane >> 3;              // level for this 8-lane group
        const int j = lane & 7;
        float e = 0.0f;
        int sz = 0;
        if (l < lmin) {
            const int st = sib_start[true_top * D + l];
            sz = sib_size[true_top * D + l];
            if (j < sz) e = expf(yp[st + j]);
        }
        e += __shfl_xor(e, 1);
        e += __shfl_xor(e, 2);
        e += __shfl_xor(e, 4);
        float contrib = 0.0f;
        if (l < lmin && j == 0) {
            const float s = e + (float)(C - sz);   // masked-out -> exp(0)=1
            const int tix = path_ids[true_top * D + l];
            const float ce = logf(s) - yp[tix];
            const float lw = expf(-DEPTH_PARAM * (float)(lt - l - 1));
            contrib = lw * ce;
        }
        contrib += __shfl_xor(contrib, 8);
        contrib += __shfl_xor(contrib, 16);
        contrib += __shfl_xor(contrib, 32);

        if (lane == 0) {
            const float diff = fabsf((float)(lp - lt));
            const float total = contrib * (LENGTH_PENALTY * diff) * class_weights[true_top];
            atomicAdd(out, total / (float)Bsz);
        }
    }
}

extern "C" void kernel_launch(void* const* d_in, const int* in_sizes, int n_in,
                              void* d_out, int out_size, void* d_ws, size_t ws_size,
                              hipStream_t stream) {
    const float* y_pred        = (const float*)d_in[0];
    const float* y_true        = (const float*)d_in[1];
    const float* class_weights = (const float*)d_in[2];
    const int*   path_ids      = (const int*)d_in[3];
    const int*   path_len      = (const int*)d_in[4];
    const int*   sib_start     = (const int*)d_in[5];
    const int*   sib_size      = (const int*)d_in[6];
    float* out = (float*)d_out;

    const int C = in_sizes[2];            // 2728
    const int D = in_sizes[3] / C;        // 5
    const int B = in_sizes[0] / C;        // 4096

    const int grid = (B + 1) / 2;         // 2 rows/block, 1 wave per (row,array)
    init_out_kernel<<<1, 1, 0, stream>>>(out);
    hier_row_kernel<<<grid, 256, 0, stream>>>(
        y_pred, y_true, class_weights, path_ids, path_len,
        sib_start, sib_size, out, C, D, B);
}

// Round 7
// 152.573 us; speedup vs baseline: 1.0975x; 1.0975x over previous
//
#include <hip/hip_runtime.h>
#include <hip/hip_bf16.h>
#include <float.h>

#define DEPTH_PARAM 0.5f
#define LENGTH_PENALTY 1.5f

#define NSLOT 64          // partial-sum slots (one per cacheline)
#define SLOT_STRIDE 16    // floats between slots = 64 B

// ws layout: float partials[NSLOT*SLOT_STRIDE], then unsigned counter.
__global__ void init_ws_kernel(float* partials, unsigned* counter, float* out) {
    const int t = threadIdx.x;
    for (int i = t; i < NSLOT * SLOT_STRIDE; i += blockDim.x) partials[i] = 0.0f;
    if (t == 0) { *counter = 0u; out[0] = 0.0f; }
}

// 256-thread block = 4 waves = 2 rows; 2 waves per row scan interleaved
// halves of BOTH arrays (R3 structure — best measured scan codegen).
// Per-block total -> atomicAdd into 1 of 64 cacheline-spaced slots
// (~32 adds/slot: no serialization, unlike the single-address atomic that
// cost R1/R4/R5/R6 ~40-70us). Last block (threadfence+counter) reads the
// slots with device-coherent atomic reads and writes mean to out[0].
__global__ __launch_bounds__(256) void hier_row_kernel(
    const float* __restrict__ y_pred,
    const float* __restrict__ y_true,
    const float* __restrict__ class_weights,
    const int* __restrict__ path_ids,
    const int* __restrict__ path_len,
    const int* __restrict__ sib_start,
    const int* __restrict__ sib_size,
    float* __restrict__ partials,
    unsigned* __restrict__ counter,
    float* __restrict__ out,
    int C, int D, int Bsz)
{
    const int wid  = threadIdx.x >> 6;       // 0..3
    const int lane = threadIdx.x & 63;
    const int half = wid & 1;                // which half of the row this wave scans
    int row = blockIdx.x * 2 + (wid >> 1);
    bool edge_dup = false;
    if (row >= Bsz) { row = Bsz - 1; edge_dup = true; }

    const float* __restrict__ yp = y_pred + (size_t)row * C;
    const float* __restrict__ yt = y_true + (size_t)row * C;
    const float4* __restrict__ yp4 = (const float4*)yp;
    const float4* __restrict__ yt4 = (const float4*)yt;

    __shared__ float s_v[4][2];
    __shared__ int   s_i[4][2];
    __shared__ float s_tot[2];
    __shared__ bool  s_last;
    if (threadIdx.x < 2) s_tot[threadIdx.x] = 0.0f;

    // ---- dual argmax, 128 threads per row, rolled loop (proven codegen) ----
    float bp = -FLT_MAX; int bip = 0;
    float bt = -FLT_MAX; int bit_ = 0;
    const int C4 = C >> 2;                   // 682 for C=2728
    for (int i = half * 64 + lane; i < C4; i += 128) {
        const float4 v = yp4[i];
        const float4 w = yt4[i];
        const int base = i << 2;
        if (v.x > bp) { bp = v.x; bip = base + 0; }
        if (v.y > bp) { bp = v.y; bip = base + 1; }
        if (v.z > bp) { bp = v.z; bip = base + 2; }
        if (v.w > bp) { bp = v.w; bip = base + 3; }
        if (w.x > bt) { bt = w.x; bit_ = base + 0; }
        if (w.y > bt) { bt = w.y; bit_ = base + 1; }
        if (w.z > bt) { bt = w.z; bit_ = base + 2; }
        if (w.w > bt) { bt = w.w; bit_ = base + 3; }
    }
    for (int c = (C4 << 2) + half * 64 + lane; c < C; c += 128) {
        const float v = yp[c]; if (v > bp) { bp = v; bip = c; }
        const float w = yt[c]; if (w > bt) { bt = w; bit_ = c; }
    }

    // ---- butterfly reduce within wave (max, first-index) ----
    for (int m = 1; m < 64; m <<= 1) {
        float ov = __shfl_xor(bp, m); int oi = __shfl_xor(bip, m);
        if (ov > bp || (ov == bp && oi < bip)) { bp = ov; bip = oi; }
        float ow = __shfl_xor(bt, m); int oj = __shfl_xor(bit_, m);
        if (ow > bt || (ow == bt && oj < bit_)) { bt = ow; bit_ = oj; }
    }

    // ---- merge the two waves of this row via LDS ----
    if (lane == 0) {
        s_v[wid][0] = bp;  s_i[wid][0] = bip;
        s_v[wid][1] = bt;  s_i[wid][1] = bit_;
    }
    __syncthreads();
    {
        const int pw = wid ^ 1;
        float ov = s_v[pw][0]; int oi = s_i[pw][0];
        if (ov > bp || (ov == bp && oi < bip)) { bp = ov; bip = oi; }
        float ow = s_v[pw][1]; int oj = s_i[pw][1];
        if (ow > bt || (ow == bt && oj < bit_)) { bt = ow; bit_ = oj; }
    }

    // ---- tail: first wave of each row pair; one 8-lane group per level ----
    if (half == 0 && !edge_dup) {
        const int pred_top = bip;
        const int true_top = bit_;
        const int lp = path_len[pred_top];
        const int lt = path_len[true_top];
        const int lmin = lp < lt ? lp : lt;

        const int l = lane >> 3;
        const int j = lane & 7;
        float e = 0.0f;
        int sz = 0;
        if (l < lmin) {
            const int st = sib_start[true_top * D + l];
            sz = sib_size[true_top * D + l];
            if (j < sz) e = expf(yp[st + j]);
        }
        e += __shfl_xor(e, 1);
        e += __shfl_xor(e, 2);
        e += __shfl_xor(e, 4);
        float contrib = 0.0f;
        if (l < lmin && j == 0) {
            const float s = e + (float)(C - sz);   // masked-out -> exp(0)=1
            const int tix = path_ids[true_top * D + l];
            const float ce = logf(s) - yp[tix];
            const float lw = expf(-DEPTH_PARAM * (float)(lt - l - 1));
            contrib = lw * ce;
        }
        contrib += __shfl_xor(contrib, 8);
        contrib += __shfl_xor(contrib, 16);
        contrib += __shfl_xor(contrib, 32);

        if (lane == 0) {
            const float diff = fabsf((float)(lp - lt));
            s_tot[wid >> 1] = contrib * (LENGTH_PENALTY * diff) * class_weights[true_top];
        }
    }
    __syncthreads();

    // ---- block total -> spread partial slot; last block finalizes ----
    if (threadIdx.x == 0) {
        const float block_sum = s_tot[0] + s_tot[1];
        atomicAdd(&partials[(blockIdx.x & (NSLOT - 1)) * SLOT_STRIDE], block_sum);
        __threadfence();
        const unsigned old = atomicAdd(counter, 1u);
        s_last = (old == gridDim.x - 1);
    }
    __syncthreads();

    if (s_last && wid == 0) {
        // device-coherent read of each slot (atomic RMW, safe across XCD L2s)
        float v = atomicAdd(&partials[lane * SLOT_STRIDE], 0.0f);
        for (int m = 1; m < 64; m <<= 1) v += __shfl_xor(v, m);
        if (lane == 0) out[0] = v / (float)Bsz;
    }
}

extern "C" void kernel_launch(void* const* d_in, const int* in_sizes, int n_in,
                              void* d_out, int out_size, void* d_ws, size_t ws_size,
                              hipStream_t stream) {
    const float* y_pred        = (const float*)d_in[0];
    const float* y_true        = (const float*)d_in[1];
    const float* class_weights = (const float*)d_in[2];
    const int*   path_ids      = (const int*)d_in[3];
    const int*   path_len      = (const int*)d_in[4];
    const int*   sib_start     = (const int*)d_in[5];
    const int*   sib_size      = (const int*)d_in[6];
    float* out = (float*)d_out;

    float*    partials = (float*)d_ws;
    unsigned* counter  = (unsigned*)((char*)d_ws + NSLOT * SLOT_STRIDE * sizeof(float));

    const int C = in_sizes[2];            // 2728
    const int D = in_sizes[3] / C;        // 5
    const int B = in_sizes[0] / C;        // 4096

    const int grid = (B + 1) / 2;         // 2 rows/block, 2 waves/row

    init_ws_kernel<<<1, 256, 0, stream>>>(partials, counter, out);
    hier_row_kernel<<<grid, 256, 0, stream>>>(
        y_pred, y_true, class_weights, path_ids, path_len,
        sib_start, sib_size, partials, counter, out, C, D, B);
}

// Round 8
// 119.586 us; speedup vs baseline: 1.4003x; 1.2758x over previous
//
#include <hip/hip_runtime.h>
#include <hip/hip_bf16.h>
#include <float.h>

#define DEPTH_PARAM 0.5f
#define LENGTH_PENALTY 1.5f

// 256-thread block = 4 waves = 2 rows; 2 waves per row scan interleaved
// halves of BOTH arrays (R3 structure — best measured scan codegen, 16 VGPR).
// NO atomics anywhere: per-block sum -> plain store to ws[blockIdx].
// (Same-address atomics measured at ~15-20ns each serialized: 4096 of them
// cost ~40us in R1/R6, 2048 cost ~30us in R7 even with L3-resident inputs.)
__global__ __launch_bounds__(256) void hier_row_kernel(
    const float* __restrict__ y_pred,
    const float* __restrict__ y_true,
    const float* __restrict__ class_weights,
    const int* __restrict__ path_ids,
    const int* __restrict__ path_len,
    const int* __restrict__ sib_start,
    const int* __restrict__ sib_size,
    float* __restrict__ block_sums,
    int C, int D, int Bsz)
{
    const int wid  = threadIdx.x >> 6;       // 0..3
    const int lane = threadIdx.x & 63;
    const int half = wid & 1;                // which half of the row this wave scans
    int row = blockIdx.x * 2 + (wid >> 1);
    bool edge_dup = false;
    if (row >= Bsz) { row = Bsz - 1; edge_dup = true; }

    const float* __restrict__ yp = y_pred + (size_t)row * C;
    const float* __restrict__ yt = y_true + (size_t)row * C;
    const float4* __restrict__ yp4 = (const float4*)yp;
    const float4* __restrict__ yt4 = (const float4*)yt;

    __shared__ float s_v[4][2];
    __shared__ int   s_i[4][2];
    __shared__ float s_tot[2];
    if (threadIdx.x < 2) s_tot[threadIdx.x] = 0.0f;

    // ---- dual argmax, 128 threads per row, rolled loop (proven codegen) ----
    float bp = -FLT_MAX; int bip = 0;
    float bt = -FLT_MAX; int bit_ = 0;
    const int C4 = C >> 2;                   // 682 for C=2728
    for (int i = half * 64 + lane; i < C4; i += 128) {
        const float4 v = yp4[i];
        const float4 w = yt4[i];
        const int base = i << 2;
        if (v.x > bp) { bp = v.x; bip = base + 0; }
        if (v.y > bp) { bp = v.y; bip = base + 1; }
        if (v.z > bp) { bp = v.z; bip = base + 2; }
        if (v.w > bp) { bp = v.w; bip = base + 3; }
        if (w.x > bt) { bt = w.x; bit_ = base + 0; }
        if (w.y > bt) { bt = w.y; bit_ = base + 1; }
        if (w.z > bt) { bt = w.z; bit_ = base + 2; }
        if (w.w > bt) { bt = w.w; bit_ = base + 3; }
    }
    for (int c = (C4 << 2) + half * 64 + lane; c < C; c += 128) {
        const float v = yp[c]; if (v > bp) { bp = v; bip = c; }
        const float w = yt[c]; if (w > bt) { bt = w; bit_ = c; }
    }

    // ---- butterfly reduce within wave (max, first-index) ----
    for (int m = 1; m < 64; m <<= 1) {
        float ov = __shfl_xor(bp, m); int oi = __shfl_xor(bip, m);
        if (ov > bp || (ov == bp && oi < bip)) { bp = ov; bip = oi; }
        float ow = __shfl_xor(bt, m); int oj = __shfl_xor(bit_, m);
        if (ow > bt || (ow == bt && oj < bit_)) { bt = ow; bit_ = oj; }
    }

    // ---- merge the two waves of this row via LDS ----
    if (lane == 0) {
        s_v[wid][0] = bp;  s_i[wid][0] = bip;
        s_v[wid][1] = bt;  s_i[wid][1] = bit_;
    }
    __syncthreads();
    {
        const int pw = wid ^ 1;
        float ov = s_v[pw][0]; int oi = s_i[pw][0];
        if (ov > bp || (ov == bp && oi < bip)) { bp = ov; bip = oi; }
        float ow = s_v[pw][1]; int oj = s_i[pw][1];
        if (ow > bt || (ow == bt && oj < bit_)) { bt = ow; bit_ = oj; }
    }

    // ---- tail: first wave of each row pair; one 8-lane group per level ----
    if (half == 0 && !edge_dup) {
        const int pred_top = bip;
        const int true_top = bit_;
        const int lp = path_len[pred_top];
        const int lt = path_len[true_top];
        const int lmin = lp < lt ? lp : lt;

        const int l = lane >> 3;
        const int j = lane & 7;
        float e = 0.0f;
        int sz = 0;
        if (l < lmin) {
            const int st = sib_start[true_top * D + l];
            sz = sib_size[true_top * D + l];
            if (j < sz) e = expf(yp[st + j]);
        }
        e += __shfl_xor(e, 1);
        e += __shfl_xor(e, 2);
        e += __shfl_xor(e, 4);
        float contrib = 0.0f;
        if (l < lmin && j == 0) {
            const float s = e + (float)(C - sz);   // masked-out -> exp(0)=1
            const int tix = path_ids[true_top * D + l];
            const float ce = logf(s) - yp[tix];
            const float lw = expf(-DEPTH_PARAM * (float)(lt - l - 1));
            contrib = lw * ce;
        }
        contrib += __shfl_xor(contrib, 8);
        contrib += __shfl_xor(contrib, 16);
        contrib += __shfl_xor(contrib, 32);

        if (lane == 0) {
            const float diff = fabsf((float)(lp - lt));
            s_tot[wid >> 1] = contrib * (LENGTH_PENALTY * diff) * class_weights[true_top];
        }
    }
    __syncthreads();

    // ---- plain store: one block sum, no atomics ----
    if (threadIdx.x == 0) {
        block_sums[blockIdx.x] = s_tot[0] + s_tot[1];
    }
}

// One block reduces the 2048 block sums (float4 reads), writes mean.
__global__ __launch_bounds__(256) void final_reduce_kernel(
    const float* __restrict__ block_sums, float* __restrict__ out,
    int nblocks, int Bsz)
{
    const int tid = threadIdx.x;
    float s = 0.0f;
    const int n4 = nblocks >> 2;
    const float4* __restrict__ bs4 = (const float4*)block_sums;
    for (int i = tid; i < n4; i += 256) {
        const float4 v = bs4[i];
        s += (v.x + v.y) + (v.z + v.w);
    }
    for (int i = (n4 << 2) + tid; i < nblocks; i += 256) s += block_sums[i];

    for (int m = 1; m < 64; m <<= 1) s += __shfl_xor(s, m);

    __shared__ float sw[4];
    const int lane = tid & 63, wid = tid >> 6;
    if (lane == 0) sw[wid] = s;
    __syncthreads();
    if (tid == 0) {
        out[0] = (sw[0] + sw[1] + sw[2] + sw[3]) / (float)Bsz;
    }
}

extern "C" void kernel_launch(void* const* d_in, const int* in_sizes, int n_in,
                              void* d_out, int out_size, void* d_ws, size_t ws_size,
                              hipStream_t stream) {
    const float* y_pred        = (const float*)d_in[0];
    const float* y_true        = (const float*)d_in[1];
    const float* class_weights = (const float*)d_in[2];
    const int*   path_ids      = (const int*)d_in[3];
    const int*   path_len      = (const int*)d_in[4];
    const int*   sib_start     = (const int*)d_in[5];
    const int*   sib_size      = (const int*)d_in[6];
    float* out = (float*)d_out;
    float* block_sums = (float*)d_ws;

    const int C = in_sizes[2];            // 2728
    const int D = in_sizes[3] / C;        // 5
    const int B = in_sizes[0] / C;        // 4096

    const int grid = (B + 1) / 2;         // 2 rows/block, 2 waves/row

    hier_row_kernel<<<grid, 256, 0, stream>>>(
        y_pred, y_true, class_weights, path_ids, path_len,
        sib_start, sib_size, block_sums, C, D, B);
    final_reduce_kernel<<<1, 256, 0, stream>>>(block_sums, out, grid, B);
}

// Round 9
// 118.228 us; speedup vs baseline: 1.4163x; 1.0115x over previous
//
#include <hip/hip_runtime.h>
#include <hip/hip_bf16.h>
#include <float.h>

#define DEPTH_PARAM 0.5f
#define LENGTH_PENALTY 1.5f

// 256-thread block = 4 waves = 2 rows; 2 waves per row scan interleaved
// halves of BOTH arrays. Software-pipelined: explicit 2-deep prefetch with
// NAMED float4s (arrays get demoted to scratch — R4/R5) and #pragma unroll 1
// (full unroll re-hoists all loads and spills — R4). 4 loads in flight/wave
// vs 2 for the rolled loop. No atomics anywhere (same-address atomics cost
// ~28ns each serialized — R1/R6/R7 evidence): block sum -> plain store.
template<int C>
__global__ __launch_bounds__(256) void hier_row_kernel_t(
    const float* __restrict__ y_pred,
    const float* __restrict__ y_true,
    const float* __restrict__ class_weights,
    const int* __restrict__ path_ids,
    const int* __restrict__ path_len,
    const int* __restrict__ sib_start,
    const int* __restrict__ sib_size,
    float* __restrict__ block_sums,
    int D, int Bsz)
{
    constexpr int C4  = C >> 2;              // 682 for C=2728
    constexpr int NIT = (C4 + 127) / 128;    // 6

    const int wid  = threadIdx.x >> 6;       // 0..3
    const int lane = threadIdx.x & 63;
    const int half = wid & 1;
    int row = blockIdx.x * 2 + (wid >> 1);
    bool edge_dup = false;
    if (row >= Bsz) { row = Bsz - 1; edge_dup = true; }

    const float* __restrict__ yp = y_pred + (size_t)row * C;
    const float* __restrict__ yt = y_true + (size_t)row * C;
    const float4* __restrict__ yp4 = (const float4*)yp;
    const float4* __restrict__ yt4 = (const float4*)yt;

    __shared__ float s_v[4][2];
    __shared__ int   s_i[4][2];
    __shared__ float s_tot[2];
    if (threadIdx.x < 2) s_tot[threadIdx.x] = 0.0f;

    const int i0 = half * 64 + lane;
    float bp = -FLT_MAX; int bip = 0;
    float bt = -FLT_MAX; int bit_ = 0;

    // prologue: load iteration 0 (clamped)
    int ic = i0 < C4 ? i0 : 0;
    float4 cv = yp4[ic];
    float4 cw = yt4[ic];

#pragma unroll 1
    for (int k = 0; k < NIT; k++) {
        // prefetch k+1 before consuming k
        float4 nv, nw;
        if (k + 1 < NIT) {
            const int i2  = i0 + (k + 1) * 128;
            const int ic2 = i2 < C4 ? i2 : 0;
            nv = yp4[ic2];
            nw = yt4[ic2];
        }
        const int ii = i0 + k * 128;
        float4 v = cv, w = cw;
        if (ii >= C4) {
            v = make_float4(-FLT_MAX, -FLT_MAX, -FLT_MAX, -FLT_MAX);
            w = v;
        }
        const int base = ii << 2;
        if (v.x > bp) { bp = v.x; bip = base + 0; }
        if (v.y > bp) { bp = v.y; bip = base + 1; }
        if (v.z > bp) { bp = v.z; bip = base + 2; }
        if (v.w > bp) { bp = v.w; bip = base + 3; }
        if (w.x > bt) { bt = w.x; bit_ = base + 0; }
        if (w.y > bt) { bt = w.y; bit_ = base + 1; }
        if (w.z > bt) { bt = w.z; bit_ = base + 2; }
        if (w.w > bt) { bt = w.w; bit_ = base + 3; }
        cv = nv; cw = nw;
    }
    if constexpr ((C & 3) != 0) {
        for (int c = (C4 << 2) + i0; c < C; c += 128) {
            const float v = yp[c]; if (v > bp) { bp = v; bip = c; }
            const float w = yt[c]; if (w > bt) { bt = w; bit_ = c; }
        }
    }

    // ---- butterfly reduce within wave (max, first-index) ----
    for (int m = 1; m < 64; m <<= 1) {
        float ov = __shfl_xor(bp, m); int oi = __shfl_xor(bip, m);
        if (ov > bp || (ov == bp && oi < bip)) { bp = ov; bip = oi; }
        float ow = __shfl_xor(bt, m); int oj = __shfl_xor(bit_, m);
        if (ow > bt || (ow == bt && oj < bit_)) { bt = ow; bit_ = oj; }
    }

    // ---- merge the two waves of this row via LDS ----
    if (lane == 0) {
        s_v[wid][0] = bp;  s_i[wid][0] = bip;
        s_v[wid][1] = bt;  s_i[wid][1] = bit_;
    }
    __syncthreads();
    {
        const int pw = wid ^ 1;
        float ov = s_v[pw][0]; int oi = s_i[pw][0];
        if (ov > bp || (ov == bp && oi < bip)) { bp = ov; bip = oi; }
        float ow = s_v[pw][1]; int oj = s_i[pw][1];
        if (ow > bt || (ow == bt && oj < bit_)) { bt = ow; bit_ = oj; }
    }

    // ---- tail: first wave of each row pair; one 8-lane group per level ----
    if (half == 0 && !edge_dup) {
        const int pred_top = bip;
        const int true_top = bit_;
        const int lp = path_len[pred_top];
        const int lt = path_len[true_top];
        const int lmin = lp < lt ? lp : lt;

        const int l = lane >> 3;
        const int j = lane & 7;
        float e = 0.0f;
        int sz = 0;
        if (l < lmin) {
            const int st = sib_start[true_top * D + l];
            sz = sib_size[true_top * D + l];
            if (j < sz) e = expf(yp[st + j]);
        }
        e += __shfl_xor(e, 1);
        e += __shfl_xor(e, 2);
        e += __shfl_xor(e, 4);
        float contrib = 0.0f;
        if (l < lmin && j == 0) {
            const float s = e + (float)(C - sz);   // masked-out -> exp(0)=1
            const int tix = path_ids[true_top * D + l];
            const float ce = logf(s) - yp[tix];
            const float lw = expf(-DEPTH_PARAM * (float)(lt - l - 1));
            contrib = lw * ce;
        }
        contrib += __shfl_xor(contrib, 8);
        contrib += __shfl_xor(contrib, 16);
        contrib += __shfl_xor(contrib, 32);

        if (lane == 0) {
            const float diff = fabsf((float)(lp - lt));
            s_tot[wid >> 1] = contrib * (LENGTH_PENALTY * diff) * class_weights[true_top];
        }
    }
    __syncthreads();

    if (threadIdx.x == 0) {
        block_sums[blockIdx.x] = s_tot[0] + s_tot[1];
    }
}

// Generic fallback (runtime C) — R8's proven rolled-loop version.
__global__ __launch_bounds__(256) void hier_row_kernel_g(
    const float* __restrict__ y_pred,
    const float* __restrict__ y_true,
    const float* __restrict__ class_weights,
    const int* __restrict__ path_ids,
    const int* __restrict__ path_len,
    const int* __restrict__ sib_start,
    const int* __restrict__ sib_size,
    float* __restrict__ block_sums,
    int C, int D, int Bsz)
{
    const int wid  = threadIdx.x >> 6;
    const int lane = threadIdx.x & 63;
    const int half = wid & 1;
    int row = blockIdx.x * 2 + (wid >> 1);
    bool edge_dup = false;
    if (row >= Bsz) { row = Bsz - 1; edge_dup = true; }

    const float* __restrict__ yp = y_pred + (size_t)row * C;
    const float* __restrict__ yt = y_true + (size_t)row * C;
    const float4* __restrict__ yp4 = (const float4*)yp;
    const float4* __restrict__ yt4 = (const float4*)yt;

    __shared__ float s_v[4][2];
    __shared__ int   s_i[4][2];
    __shared__ float s_tot[2];
    if (threadIdx.x < 2) s_tot[threadIdx.x] = 0.0f;

    float bp = -FLT_MAX; int bip = 0;
    float bt = -FLT_MAX; int bit_ = 0;
    const int C4 = C >> 2;
    for (int i = half * 64 + lane; i < C4; i += 128) {
        const float4 v = yp4[i];
        const float4 w = yt4[i];
        const int base = i << 2;
        if (v.x > bp) { bp = v.x; bip = base + 0; }
        if (v.y > bp) { bp = v.y; bip = base + 1; }
        if (v.z > bp) { bp = v.z; bip = base + 2; }
        if (v.w > bp) { bp = v.w; bip = base + 3; }
        if (w.x > bt) { bt = w.x; bit_ = base + 0; }
        if (w.y > bt) { bt = w.y; bit_ = base + 1; }
        if (w.z > bt) { bt = w.z; bit_ = base + 2; }
        if (w.w > bt) { bt = w.w; bit_ = base + 3; }
    }
    for (int c = (C4 << 2) + half * 64 + lane; c < C; c += 128) {
        const float v = yp[c]; if (v > bp) { bp = v; bip = c; }
        const float w = yt[c]; if (w > bt) { bt = w; bit_ = c; }
    }
    for (int m = 1; m < 64; m <<= 1) {
        float ov = __shfl_xor(bp, m); int oi = __shfl_xor(bip, m);
        if (ov > bp || (ov == bp && oi < bip)) { bp = ov; bip = oi; }
        float ow = __shfl_xor(bt, m); int oj = __shfl_xor(bit_, m);
        if (ow > bt || (ow == bt && oj < bit_)) { bt = ow; bit_ = oj; }
    }
    if (lane == 0) {
        s_v[wid][0] = bp;  s_i[wid][0] = bip;
        s_v[wid][1] = bt;  s_i[wid][1] = bit_;
    }
    __syncthreads();
    {
        const int pw = wid ^ 1;
        float ov = s_v[pw][0]; int oi = s_i[pw][0];
        if (ov > bp || (ov == bp && oi < bip)) { bp = ov; bip = oi; }
        float ow = s_v[pw][1]; int oj = s_i[pw][1];
        if (ow > bt || (ow == bt && oj < bit_)) { bt = ow; bit_ = oj; }
    }
    if (half == 0 && !edge_dup) {
        const int pred_top = bip;
        const int true_top = bit_;
        const int lp = path_len[pred_top];
        const int lt = path_len[true_top];
        const int lmin = lp < lt ? lp : lt;
        const int l = lane >> 3;
        const int j = lane & 7;
        float e = 0.0f;
        int sz = 0;
        if (l < lmin) {
            const int st = sib_start[true_top * D + l];
            sz = sib_size[true_top * D + l];
            if (j < sz) e = expf(yp[st + j]);
        }
        e += __shfl_xor(e, 1);
        e += __shfl_xor(e, 2);
        e += __shfl_xor(e, 4);
        float contrib = 0.0f;
        if (l < lmin && j == 0) {
            const float s = e + (float)(C - sz);
            const int tix = path_ids[true_top * D + l];
            const float ce = logf(s) - yp[tix];
            const float lw = expf(-DEPTH_PARAM * (float)(lt - l - 1));
            contrib = lw * ce;
        }
        contrib += __shfl_xor(contrib, 8);
        contrib += __shfl_xor(contrib, 16);
        contrib += __shfl_xor(contrib, 32);
        if (lane == 0) {
            const float diff = fabsf((float)(lp - lt));
            s_tot[wid >> 1] = contrib * (LENGTH_PENALTY * diff) * class_weights[true_top];
        }
    }
    __syncthreads();
    if (threadIdx.x == 0) {
        block_sums[blockIdx.x] = s_tot[0] + s_tot[1];
    }
}

// One block reduces the block sums (float4 reads), writes mean.
__global__ __launch_bounds__(256) void final_reduce_kernel(
    const float* __restrict__ block_sums, float* __restrict__ out,
    int nblocks, int Bsz)
{
    const int tid = threadIdx.x;
    float s = 0.0f;
    const int n4 = nblocks >> 2;
    const float4* __restrict__ bs4 = (const float4*)block_sums;
    for (int i = tid; i < n4; i += 256) {
        const float4 v = bs4[i];
        s += (v.x + v.y) + (v.z + v.w);
    }
    for (int i = (n4 << 2) + tid; i < nblocks; i += 256) s += block_sums[i];

    for (int m = 1; m < 64; m <<= 1) s += __shfl_xor(s, m);

    __shared__ float sw[4];
    const int lane = tid & 63, wid = tid >> 6;
    if (lane == 0) sw[wid] = s;
    __syncthreads();
    if (tid == 0) {
        out[0] = (sw[0] + sw[1] + sw[2] + sw[3]) / (float)Bsz;
    }
}

extern "C" void kernel_launch(void* const* d_in, const int* in_sizes, int n_in,
                              void* d_out, int out_size, void* d_ws, size_t ws_size,
                              hipStream_t stream) {
    const float* y_pred        = (const float*)d_in[0];
    const float* y_true        = (const float*)d_in[1];
    const float* class_weights = (const float*)d_in[2];
    const int*   path_ids      = (const int*)d_in[3];
    const int*   path_len      = (const int*)d_in[4];
    const int*   sib_start     = (const int*)d_in[5];
    const int*   sib_size      = (const int*)d_in[6];
    float* out = (float*)d_out;
    float* block_sums = (float*)d_ws;

    const int C = in_sizes[2];            // 2728
    const int D = in_sizes[3] / C;        // 5
    const int B = in_sizes[0] / C;        // 4096

    const int grid = (B + 1) / 2;         // 2 rows/block, 2 waves/row

    if (C == 2728) {
        hier_row_kernel_t<2728><<<grid, 256, 0, stream>>>(
            y_pred, y_true, class_weights, path_ids, path_len,
            sib_start, sib_size, block_sums, D, B);
    } else {
        hier_row_kernel_g<<<grid, 256, 0, stream>>>(
            y_pred, y_true, class_weights, path_ids, path_len,
            sib_start, sib_size, block_sums, C, D, B);
    }
    final_reduce_kernel<<<1, 256, 0, stream>>>(block_sums, out, grid, B);
}